// Round 15
// baseline (116.402 us; speedup 1.0000x reference)
//
#include <hip/hip_runtime.h>
#include <hip/hip_fp16.h>
#include <math.h>

#define N_NODES 50000
#define N_EDGES 800000
#define D 128
#define BN_EPS 1e-5f
#define N_TILES 3125   // 50000 / 16
#define CAP 64         // max degree capacity (Poisson(16); P(deg>64) ~ 1e-19)
#define SPMM_BLOCKS 2048
#define SCOLS 32       // columns per XCD-pinned slice (3.2 MB fp16 -> fits 4 MiB L2)
#define RROWS 6250     // N_NODES / 8: rows per XCD group
#define SC_THREADS 384 // scatter threads per block (waves 2..7)
#define SC_STRIDE (256 * SC_THREADS)   // 98304 lanes per XCD group
#define N_REC (N_EDGES / 2)            // 400000 16B records (2 edges each)
#define CSTR 16        // cnt padding: one counter per 64B line (atomic line-contention fix)

typedef __attribute__((ext_vector_type(8))) _Float16 half8;
typedef __attribute__((ext_vector_type(4))) float floatx4;
typedef __attribute__((ext_vector_type(4))) unsigned uintx4;   // nt-load-compatible

// ---------------- octonion Hamilton tables ----------------
__device__ __constant__ int OCT_C[8][8] = {
    {0,1,2,3,4,5,6,7},
    {1,0,3,2,5,4,7,6},
    {2,3,0,1,6,7,4,5},
    {3,2,1,0,7,6,5,4},
    {4,5,6,7,0,1,2,3},
    {5,4,7,6,1,0,3,2},
    {6,7,4,5,2,3,0,1},
    {7,6,5,4,3,2,1,0}};
__device__ __constant__ float OCT_S[8][8] = {
    { 1,-1,-1,-1,-1,-1,-1,-1},
    { 1, 1,-1, 1,-1, 1, 1,-1},
    { 1, 1, 1,-1,-1,-1, 1, 1},
    { 1,-1, 1, 1,-1, 1,-1, 1},
    { 1, 1, 1, 1, 1,-1,-1,-1},
    { 1,-1, 1,-1, 1, 1, 1,-1},
    { 1,-1,-1, 1, 1,-1, 1, 1},
    { 1, 1,-1,-1, 1, 1,-1, 1}};

// ---------------- k1: setup (Ht, zero padded cnt/stats) + pack epack ----------------
__global__ __launch_bounds__(256) void setup_pack_kernel(const float* __restrict__ W,
                                                         __half* __restrict__ Ht,
                                                         int* __restrict__ cnt,
                                                         float* __restrict__ stats,
                                                         const int* __restrict__ arow,
                                                         const int* __restrict__ acol,
                                                         const float* __restrict__ aval,
                                                         uint2* __restrict__ epack) {
    const int i = blockIdx.x * 256 + threadIdx.x;
    const int nthreads = gridDim.x * 256;
    if (i < D * D) {
        int ccol = i >> 7, k = i & 127;
        int ii = k >> 4, kw = k & 15, j = ccol >> 4, m = ccol & 15;
        Ht[i] = __float2half(OCT_S[j][ii] * W[kw * D + OCT_C[j][ii] * 16 + m]);
    }
    for (int j = i; j < N_NODES * CSTR; j += nthreads) cnt[j] = 0;
    if (i < 2 * D) stats[i] = 0.0f;
    const int base = i * 4;
    if (base + 4 <= N_EDGES) {
        int4   r4 = *reinterpret_cast<const int4*>(arow + base);
        int4   c4 = *reinterpret_cast<const int4*>(acol + base);
        float4 v4 = *reinterpret_cast<const float4*>(aval + base);
        uint2 o[4];
        o[0] = make_uint2(((unsigned)c4.x & 0xFFFFu) | ((unsigned)__half_as_ushort(__float2half(v4.x)) << 16), (unsigned)r4.x);
        o[1] = make_uint2(((unsigned)c4.y & 0xFFFFu) | ((unsigned)__half_as_ushort(__float2half(v4.y)) << 16), (unsigned)r4.y);
        o[2] = make_uint2(((unsigned)c4.z & 0xFFFFu) | ((unsigned)__half_as_ushort(__float2half(v4.z)) << 16), (unsigned)r4.z);
        o[3] = make_uint2(((unsigned)c4.w & 0xFFFFu) | ((unsigned)__half_as_ushort(__float2half(v4.w)) << 16), (unsigned)r4.w);
        reinterpret_cast<uint4*>(epack + base)[0] = *reinterpret_cast<uint4*>(&o[0]);
        reinterpret_cast<uint4*>(epack + base)[1] = *reinterpret_cast<uint4*>(&o[2]);
    }
}

// ---------------- k2: wave-split fusion — waves 0-1 gemm, waves 2-7 scatter ----------------
// cnt is padded to one counter per 64B line: same-line atomic RMW serialization
// (the hypothesized 53us floor) is removed; atomics to distinct lines pipeline.
__global__ __launch_bounds__(512) void gemm_scatter_kernel(const uint2* __restrict__ epack,
                                                           int* __restrict__ cnt,
                                                           unsigned* __restrict__ bucket,
                                                           const float* __restrict__ in,
                                                           const __half* __restrict__ Ht,
                                                           __half* __restrict__ support) {
    const int b = blockIdx.x;
    const int tid = threadIdx.x;
    if (tid >= 128) {
        // ---- scatter (waves 2..7), XCD-pinned ----
        const int g = b & 7;
        const int rank = b >> 3;                 // 0..255 within group
        const int r0 = g * RROWS, r1 = r0 + RROWS;
        const uintx4* ep4 = reinterpret_cast<const uintx4*>(epack);   // 2 edges/record
        int i = rank * SC_THREADS + (tid - 128);
        for (; i + SC_STRIDE < N_REC; i += 2 * SC_STRIDE) {
            uintx4 ea = __builtin_nontemporal_load(ep4 + i);
            uintx4 eb = __builtin_nontemporal_load(ep4 + i + SC_STRIDE);
            int r;
            r = (int)ea.y;
            if (r >= r0 && r < r1) {
                int slot = atomicAdd(&cnt[r * CSTR], 1);
                if (slot < CAP) bucket[(size_t)r * CAP + slot] = ea.x;
            }
            r = (int)ea.w;
            if (r >= r0 && r < r1) {
                int slot = atomicAdd(&cnt[r * CSTR], 1);
                if (slot < CAP) bucket[(size_t)r * CAP + slot] = ea.z;
            }
            r = (int)eb.y;
            if (r >= r0 && r < r1) {
                int slot = atomicAdd(&cnt[r * CSTR], 1);
                if (slot < CAP) bucket[(size_t)r * CAP + slot] = eb.x;
            }
            r = (int)eb.w;
            if (r >= r0 && r < r1) {
                int slot = atomicAdd(&cnt[r * CSTR], 1);
                if (slot < CAP) bucket[(size_t)r * CAP + slot] = eb.z;
            }
        }
        for (; i < N_REC; i += SC_STRIDE) {
            uintx4 ea = __builtin_nontemporal_load(ep4 + i);
            int r = (int)ea.y;
            if (r >= r0 && r < r1) {
                int slot = atomicAdd(&cnt[r * CSTR], 1);
                if (slot < CAP) bucket[(size_t)r * CAP + slot] = ea.x;
            }
            r = (int)ea.w;
            if (r >= r0 && r < r1) {
                int slot = atomicAdd(&cnt[r * CSTR], 1);
                if (slot < CAP) bucket[(size_t)r * CAP + slot] = ea.z;
            }
        }
        return;
    }
    // ---- gemm (waves 0,1): tile = b*2 + wave ----
    const int wv = tid >> 6;
    const int tile = b * 2 + wv;
    if (tile >= N_TILES) return;
    const int lane = tid & 63;
    const int s = lane & 15;
    const int t = lane >> 4;

    half8 bb[8][4];
#pragma unroll
    for (int kk = 0; kk < 4; ++kk)
#pragma unroll
        for (int n = 0; n < 8; ++n)
            bb[n][kk] = *reinterpret_cast<const half8*>(Ht + (size_t)(16 * n + s) * D + kk * 32 + 8 * t);

    const float* ap = in + (size_t)(tile * 16 + s) * D;
    half8 a[4];
#pragma unroll
    for (int kk = 0; kk < 4; ++kk) {
        float4 f0 = *reinterpret_cast<const float4*>(ap + kk * 32 + 8 * t);
        float4 f1 = *reinterpret_cast<const float4*>(ap + kk * 32 + 8 * t + 4);
        a[kk][0] = (_Float16)f0.x; a[kk][1] = (_Float16)f0.y;
        a[kk][2] = (_Float16)f0.z; a[kk][3] = (_Float16)f0.w;
        a[kk][4] = (_Float16)f1.x; a[kk][5] = (_Float16)f1.y;
        a[kk][6] = (_Float16)f1.z; a[kk][7] = (_Float16)f1.w;
    }

    floatx4 acc[8];
#pragma unroll
    for (int n = 0; n < 8; ++n) acc[n] = (floatx4){0.f, 0.f, 0.f, 0.f};
#pragma unroll
    for (int kk = 0; kk < 4; ++kk)
#pragma unroll
        for (int n = 0; n < 8; ++n)
            acc[n] = __builtin_amdgcn_mfma_f32_16x16x32_f16(a[kk], bb[n][kk], acc[n], 0, 0, 0);

    __half* sp = support + (size_t)(tile * 16 + 4 * t) * D + s;
#pragma unroll
    for (int r = 0; r < 4; ++r)
#pragma unroll
        for (int n = 0; n < 8; ++n)
            sp[(size_t)r * D + 16 * n] = __float2half(acc[n][r]);
}

// ---------------- XCD-sliced bucket spmm, 2 rows/wave, pk_fma_f16 (R9 known-good) ----------------
__global__ __launch_bounds__(256) void spmm_kernel(const __half* __restrict__ support,
                                                   const int* __restrict__ cnt,
                                                   const unsigned* __restrict__ bucket,
                                                   __half* __restrict__ outh,
                                                   float* __restrict__ colsum,
                                                   float* __restrict__ colsq) {
    const int tid = threadIdx.x;
    const int lane = tid & 63;
    const int wv = tid >> 6;
    const int h = lane >> 4;          // edge group 0..3
    const int cl = lane & 15;         // column lane
    const int b = blockIdx.x;
    const int slice = (b & 7) >> 1;
    const int rank = ((b >> 3) << 1) | (b & 1);   // 0..511 within slice
    const int nrank = SPMM_BLOCKS >> 2;           // 512
    const int colbase = slice * SCOLS + cl * 2;

    __shared__ float lsum[SCOLS], lsq[SCOLS];
    if (tid < SCOLS) { lsum[tid] = 0.f; lsq[tid] = 0.f; }
    __syncthreads();

    float s0 = 0.f, s1 = 0.f, q0 = 0.f, q1 = 0.f;

    for (int row = rank * 8 + wv * 2; row < N_NODES; row += nrank * 8) {
        const int rowb = row + 1;
        int na = cnt[row * CSTR]; na = na < CAP ? na : CAP;
        int nb = (rowb < N_NODES) ? cnt[rowb * CSTR] : 0; nb = nb < CAP ? nb : CAP;
        const unsigned ewa = (lane < na) ? bucket[(size_t)row * CAP + lane] : 0u;
        const unsigned ewb = (lane < nb) ? bucket[(size_t)rowb * CAP + lane] : 0u;
        __half2 acca = __half2half2(__ushort_as_half((unsigned short)0));
        __half2 accb = acca;
        const int nmax = na > nb ? na : nb;
        const int n16 = (nmax + 15) & ~15;
        for (int e = 0; e < n16; e += 16) {
            unsigned ua[4], ub[4];
            __half2 ga[4], gb[4];
#pragma unroll
            for (int j = 0; j < 4; ++j) {
                int idx = e + j * 4 + h;
                ua[j] = __shfl(ewa, idx);       // idx>=n lanes broadcast 0 -> col0,val0
                ub[j] = __shfl(ewb, idx);
            }
#pragma unroll
            for (int j = 0; j < 4; ++j) {
                ga[j] = *reinterpret_cast<const __half2*>(support + (size_t)(ua[j] & 0xFFFFu) * D + colbase);
                gb[j] = *reinterpret_cast<const __half2*>(support + (size_t)(ub[j] & 0xFFFFu) * D + colbase);
            }
#pragma unroll
            for (int j = 0; j < 4; ++j) {
                unsigned va2 = __builtin_amdgcn_perm(ua[j], ua[j], 0x07060706u); // (val,val)
                unsigned vb2 = __builtin_amdgcn_perm(ub[j], ub[j], 0x07060706u);
                acca = __hfma2(*reinterpret_cast<__half2*>(&va2), ga[j], acca);
                accb = __hfma2(*reinterpret_cast<__half2*>(&vb2), gb[j], accb);
            }
        }
        // combine the 4 edge groups
#pragma unroll
        for (int off = 16; off <= 32; off <<= 1) {
            int ia = __shfl_xor(*reinterpret_cast<int*>(&acca), off);
            int ib = __shfl_xor(*reinterpret_cast<int*>(&accb), off);
            acca = __hadd2(acca, *reinterpret_cast<__half2*>(&ia));
            accb = __hadd2(accb, *reinterpret_cast<__half2*>(&ib));
        }
        if (h == 0) {
            float2 fa = __half22float2(acca);
            *reinterpret_cast<__half2*>(outh + (size_t)row * D + colbase) = acca;
            s0 += fa.x; s1 += fa.y; q0 += fa.x * fa.x; q1 += fa.y * fa.y;
            if (rowb < N_NODES) {
                float2 fb = __half22float2(accb);
                *reinterpret_cast<__half2*>(outh + (size_t)rowb * D + colbase) = accb;
                s0 += fb.x; s1 += fb.y; q0 += fb.x * fb.x; q1 += fb.y * fb.y;
            }
        }
    }

    if (h == 0) {
        atomicAdd(&lsum[cl * 2 + 0], s0); atomicAdd(&lsum[cl * 2 + 1], s1);
        atomicAdd(&lsq[cl * 2 + 0], q0);  atomicAdd(&lsq[cl * 2 + 1], q1);
    }
    __syncthreads();
    if (tid < SCOLS) {
        atomicAdd(&colsum[slice * SCOLS + tid], lsum[tid]);
        atomicAdd(&colsq[slice * SCOLS + tid], lsq[tid]);
    }
}

// ---------------- BN + tanh: read fp16 outh, write fp32 out ----------------
__global__ __launch_bounds__(256) void bn_tanh_kernel(const __half* __restrict__ outh,
                                                      float* __restrict__ out,
                                                      const float* __restrict__ colsum,
                                                      const float* __restrict__ colsq,
                                                      const float* __restrict__ gamma,
                                                      const float* __restrict__ beta) {
    __shared__ float scale[D], shift[D];
    const int tid = threadIdx.x;
    if (tid < D) {
        float mean = colsum[tid] * (1.0f / N_NODES);
        float var  = colsq[tid] * (1.0f / N_NODES) - mean * mean;
        float sc   = rsqrtf(var + BN_EPS) * gamma[tid];
        scale[tid] = sc;
        shift[tid] = beta[tid] - mean * sc;
    }
    __syncthreads();
    const int nq = N_NODES * D / 8;   // units of 8 halves
    for (int i = blockIdx.x * 256 + tid; i < nq; i += gridDim.x * 256) {
        uint4 v = reinterpret_cast<const uint4*>(outh)[i];
        const int c = (i & 15) * 8;
        float r[8];
        float2 f;
        f = __half22float2(*reinterpret_cast<__half2*>(&v.x)); r[0] = f.x; r[1] = f.y;
        f = __half22float2(*reinterpret_cast<__half2*>(&v.y)); r[2] = f.x; r[3] = f.y;
        f = __half22float2(*reinterpret_cast<__half2*>(&v.z)); r[4] = f.x; r[5] = f.y;
        f = __half22float2(*reinterpret_cast<__half2*>(&v.w)); r[6] = f.x; r[7] = f.y;
#pragma unroll
        for (int k = 0; k < 8; ++k) {
            float x = r[k] * scale[c + k] + shift[c + k];
            float e = __expf(2.0f * x);
            r[k] = 1.0f - 2.0f / (1.0f + e);
        }
        float4 o0 = make_float4(r[0], r[1], r[2], r[3]);
        float4 o1 = make_float4(r[4], r[5], r[6], r[7]);
        reinterpret_cast<float4*>(out)[i * 2 + 0] = o0;
        reinterpret_cast<float4*>(out)[i * 2 + 1] = o1;
    }
}

// ---------------- launch ----------------
extern "C" void kernel_launch(void* const* d_in, const int* in_sizes, int n_in,
                              void* d_out, int out_size, void* d_ws, size_t ws_size,
                              hipStream_t stream) {
    const float* input  = (const float*)d_in[0];
    const int*   arow   = (const int*)d_in[1];
    const int*   acol   = (const int*)d_in[2];
    const float* aval   = (const float*)d_in[3];
    const float* weight = (const float*)d_in[4];
    const float* gamma  = (const float*)d_in[5];
    const float* beta   = (const float*)d_in[6];
    float* out = (float*)d_out;

    __half*   support = (__half*)d_ws;                              // 12.8 MB
    unsigned* bucket  = (unsigned*)(support + (size_t)N_NODES * D); // 12.8 MB
    __half*   outh    = (__half*)(bucket + (size_t)N_NODES * CAP);  // 12.8 MB
    uint2*    epack   = (uint2*)outh;                               // aliases outh (consumed before spmm writes)
    int*      cnt     = (int*)(outh + (size_t)N_NODES * D);         // 3.2 MB (padded: 1 counter / 64B line)
    float*    colsum  = (float*)(cnt + (size_t)N_NODES * CSTR);     // 128 (+128 colsq)
    __half*   Ht      = (__half*)(colsum + 2 * D);                  // 32 KB

    setup_pack_kernel<<<782, 256, 0, stream>>>(weight, Ht, cnt, colsum,
                                               arow, acol, aval, epack);
    gemm_scatter_kernel<<<SPMM_BLOCKS, 512, 0, stream>>>(epack, cnt, bucket,
                                                         input, Ht, support);
    spmm_kernel<<<SPMM_BLOCKS, 256, 0, stream>>>(support, cnt, bucket, outh, colsum, colsum + D);
    bn_tanh_kernel<<<2048, 256, 0, stream>>>(outh, out, colsum, colsum + D, gamma, beta);
}

// Round 16
// 113.014 us; speedup vs baseline: 1.0300x; 1.0300x over previous
//
#include <hip/hip_runtime.h>
#include <hip/hip_fp16.h>
#include <math.h>

#define N_NODES 50000
#define N_EDGES 800000
#define D 128
#define BN_EPS 1e-5f
#define N_TILES 3125   // 50000 / 16
#define CAP 64         // max degree capacity (Poisson(16); P(deg>64) ~ 1e-19)
#define SPMM_BLOCKS 2048
#define SCOLS 32       // columns per XCD-pinned slice (3.2 MB fp16 -> fits 4 MiB L2)
#define RROWS 6250     // N_NODES / 8: rows per XCD group
#define SC_THREADS 384 // scatter threads per block (waves 2..7)
#define SC_STRIDE (256 * SC_THREADS)   // 98304 lanes per XCD group
#define N_REC (N_EDGES / 2)            // 400000 16B records (2 edges each)

typedef __attribute__((ext_vector_type(8))) _Float16 half8;
typedef __attribute__((ext_vector_type(4))) float floatx4;
typedef __attribute__((ext_vector_type(4))) unsigned uintx4;   // nt-load-compatible

// ---------------- octonion Hamilton tables ----------------
__device__ __constant__ int OCT_C[8][8] = {
    {0,1,2,3,4,5,6,7},
    {1,0,3,2,5,4,7,6},
    {2,3,0,1,6,7,4,5},
    {3,2,1,0,7,6,5,4},
    {4,5,6,7,0,1,2,3},
    {5,4,7,6,1,0,3,2},
    {6,7,4,5,2,3,0,1},
    {7,6,5,4,3,2,1,0}};
__device__ __constant__ float OCT_S[8][8] = {
    { 1,-1,-1,-1,-1,-1,-1,-1},
    { 1, 1,-1, 1,-1, 1, 1,-1},
    { 1, 1, 1,-1,-1,-1, 1, 1},
    { 1,-1, 1, 1,-1, 1,-1, 1},
    { 1, 1, 1, 1, 1,-1,-1,-1},
    { 1,-1, 1,-1, 1, 1, 1,-1},
    { 1,-1,-1, 1, 1,-1, 1, 1},
    { 1, 1,-1,-1, 1, 1,-1, 1}};

// ---------------- k1: setup (Ht, zero cnt/stats) + pack epack ----------------
__global__ __launch_bounds__(256) void setup_pack_kernel(const float* __restrict__ W,
                                                         __half* __restrict__ Ht,
                                                         int* __restrict__ cnt,
                                                         float* __restrict__ stats,
                                                         const int* __restrict__ arow,
                                                         const int* __restrict__ acol,
                                                         const float* __restrict__ aval,
                                                         uint2* __restrict__ epack) {
    const int i = blockIdx.x * 256 + threadIdx.x;
    if (i < D * D) {
        int ccol = i >> 7, k = i & 127;
        int ii = k >> 4, kw = k & 15, j = ccol >> 4, m = ccol & 15;
        Ht[i] = __float2half(OCT_S[j][ii] * W[kw * D + OCT_C[j][ii] * 16 + m]);
    }
    if (i < N_NODES) cnt[i] = 0;
    if (i < 2 * D) stats[i] = 0.0f;
    const int base = i * 4;
    if (base + 4 <= N_EDGES) {
        int4   r4 = *reinterpret_cast<const int4*>(arow + base);
        int4   c4 = *reinterpret_cast<const int4*>(acol + base);
        float4 v4 = *reinterpret_cast<const float4*>(aval + base);
        uint2 o[4];
        o[0] = make_uint2(((unsigned)c4.x & 0xFFFFu) | ((unsigned)__half_as_ushort(__float2half(v4.x)) << 16), (unsigned)r4.x);
        o[1] = make_uint2(((unsigned)c4.y & 0xFFFFu) | ((unsigned)__half_as_ushort(__float2half(v4.y)) << 16), (unsigned)r4.y);
        o[2] = make_uint2(((unsigned)c4.z & 0xFFFFu) | ((unsigned)__half_as_ushort(__float2half(v4.z)) << 16), (unsigned)r4.z);
        o[3] = make_uint2(((unsigned)c4.w & 0xFFFFu) | ((unsigned)__half_as_ushort(__float2half(v4.w)) << 16), (unsigned)r4.w);
        reinterpret_cast<uint4*>(epack + base)[0] = *reinterpret_cast<uint4*>(&o[0]);
        reinterpret_cast<uint4*>(epack + base)[1] = *reinterpret_cast<uint4*>(&o[2]);
    }
}

// ---------------- k2: wave-split fusion — waves 0-1 gemm (nt streams), waves 2-7 scatter ----------------
// gemm's input loads and support stores are NONTEMPORAL so they don't allocate
// in L2: the 1.6 MB/XCD bucket slice stays resident and its 64B lines fill
// completely before writeback (kills the 44.8 MB write amplification).
__global__ __launch_bounds__(512) void gemm_scatter_kernel(const uint2* __restrict__ epack,
                                                           int* __restrict__ cnt,
                                                           unsigned* __restrict__ bucket,
                                                           const float* __restrict__ in,
                                                           const __half* __restrict__ Ht,
                                                           __half* __restrict__ support) {
    const int b = blockIdx.x;
    const int tid = threadIdx.x;
    if (tid >= 128) {
        // ---- scatter (waves 2..7), XCD-pinned ----
        const int g = b & 7;
        const int rank = b >> 3;                 // 0..255 within group
        const int r0 = g * RROWS, r1 = r0 + RROWS;
        const uintx4* ep4 = reinterpret_cast<const uintx4*>(epack);   // 2 edges/record
        int i = rank * SC_THREADS + (tid - 128);
        for (; i + SC_STRIDE < N_REC; i += 2 * SC_STRIDE) {
            uintx4 ea = __builtin_nontemporal_load(ep4 + i);
            uintx4 eb = __builtin_nontemporal_load(ep4 + i + SC_STRIDE);
            int r;
            r = (int)ea.y;
            if (r >= r0 && r < r1) {
                int slot = atomicAdd(&cnt[r], 1);
                if (slot < CAP) bucket[(size_t)r * CAP + slot] = ea.x;
            }
            r = (int)ea.w;
            if (r >= r0 && r < r1) {
                int slot = atomicAdd(&cnt[r], 1);
                if (slot < CAP) bucket[(size_t)r * CAP + slot] = ea.z;
            }
            r = (int)eb.y;
            if (r >= r0 && r < r1) {
                int slot = atomicAdd(&cnt[r], 1);
                if (slot < CAP) bucket[(size_t)r * CAP + slot] = eb.x;
            }
            r = (int)eb.w;
            if (r >= r0 && r < r1) {
                int slot = atomicAdd(&cnt[r], 1);
                if (slot < CAP) bucket[(size_t)r * CAP + slot] = eb.z;
            }
        }
        for (; i < N_REC; i += SC_STRIDE) {
            uintx4 ea = __builtin_nontemporal_load(ep4 + i);
            int r = (int)ea.y;
            if (r >= r0 && r < r1) {
                int slot = atomicAdd(&cnt[r], 1);
                if (slot < CAP) bucket[(size_t)r * CAP + slot] = ea.x;
            }
            r = (int)ea.w;
            if (r >= r0 && r < r1) {
                int slot = atomicAdd(&cnt[r], 1);
                if (slot < CAP) bucket[(size_t)r * CAP + slot] = ea.z;
            }
        }
        return;
    }
    // ---- gemm (waves 0,1): tile = b*2 + wave ----
    const int wv = tid >> 6;
    const int tile = b * 2 + wv;
    if (tile >= N_TILES) return;
    const int lane = tid & 63;
    const int s = lane & 15;
    const int t = lane >> 4;

    half8 bb[8][4];
#pragma unroll
    for (int kk = 0; kk < 4; ++kk)
#pragma unroll
        for (int n = 0; n < 8; ++n)
            bb[n][kk] = *reinterpret_cast<const half8*>(Ht + (size_t)(16 * n + s) * D + kk * 32 + 8 * t);

    const floatx4* ap = reinterpret_cast<const floatx4*>(in + (size_t)(tile * 16 + s) * D);
    half8 a[4];
#pragma unroll
    for (int kk = 0; kk < 4; ++kk) {
        floatx4 f0 = __builtin_nontemporal_load(ap + kk * 8 + 2 * t);      // (kk*32 + 8t)/4
        floatx4 f1 = __builtin_nontemporal_load(ap + kk * 8 + 2 * t + 1);
        a[kk][0] = (_Float16)f0.x; a[kk][1] = (_Float16)f0.y;
        a[kk][2] = (_Float16)f0.z; a[kk][3] = (_Float16)f0.w;
        a[kk][4] = (_Float16)f1.x; a[kk][5] = (_Float16)f1.y;
        a[kk][6] = (_Float16)f1.z; a[kk][7] = (_Float16)f1.w;
    }

    floatx4 acc[8];
#pragma unroll
    for (int n = 0; n < 8; ++n) acc[n] = (floatx4){0.f, 0.f, 0.f, 0.f};
#pragma unroll
    for (int kk = 0; kk < 4; ++kk)
#pragma unroll
        for (int n = 0; n < 8; ++n)
            acc[n] = __builtin_amdgcn_mfma_f32_16x16x32_f16(a[kk], bb[n][kk], acc[n], 0, 0, 0);

    __half* sp = support + (size_t)(tile * 16 + 4 * t) * D + s;
#pragma unroll
    for (int r = 0; r < 4; ++r)
#pragma unroll
        for (int n = 0; n < 8; ++n) {
            __half hv = __float2half(acc[n][r]);
            __builtin_nontemporal_store(__half_as_ushort(hv),
                reinterpret_cast<unsigned short*>(sp + (size_t)r * D + 16 * n));
        }
}

// ---------------- XCD-sliced bucket spmm, 2 rows/wave, pk_fma_f16 (R9 known-good) ----------------
__global__ __launch_bounds__(256) void spmm_kernel(const __half* __restrict__ support,
                                                   const int* __restrict__ cnt,
                                                   const unsigned* __restrict__ bucket,
                                                   __half* __restrict__ outh,
                                                   float* __restrict__ colsum,
                                                   float* __restrict__ colsq) {
    const int tid = threadIdx.x;
    const int lane = tid & 63;
    const int wv = tid >> 6;
    const int h = lane >> 4;          // edge group 0..3
    const int cl = lane & 15;         // column lane
    const int b = blockIdx.x;
    const int slice = (b & 7) >> 1;
    const int rank = ((b >> 3) << 1) | (b & 1);   // 0..511 within slice
    const int nrank = SPMM_BLOCKS >> 2;           // 512
    const int colbase = slice * SCOLS + cl * 2;

    __shared__ float lsum[SCOLS], lsq[SCOLS];
    if (tid < SCOLS) { lsum[tid] = 0.f; lsq[tid] = 0.f; }
    __syncthreads();

    float s0 = 0.f, s1 = 0.f, q0 = 0.f, q1 = 0.f;

    for (int row = rank * 8 + wv * 2; row < N_NODES; row += nrank * 8) {
        const int rowb = row + 1;
        int na = cnt[row]; na = na < CAP ? na : CAP;
        int nb = (rowb < N_NODES) ? cnt[rowb] : 0; nb = nb < CAP ? nb : CAP;
        const unsigned ewa = (lane < na) ? bucket[(size_t)row * CAP + lane] : 0u;
        const unsigned ewb = (lane < nb) ? bucket[(size_t)rowb * CAP + lane] : 0u;
        __half2 acca = __half2half2(__ushort_as_half((unsigned short)0));
        __half2 accb = acca;
        const int nmax = na > nb ? na : nb;
        const int n16 = (nmax + 15) & ~15;
        for (int e = 0; e < n16; e += 16) {
            unsigned ua[4], ub[4];
            __half2 ga[4], gb[4];
#pragma unroll
            for (int j = 0; j < 4; ++j) {
                int idx = e + j * 4 + h;
                ua[j] = __shfl(ewa, idx);       // idx>=n lanes broadcast 0 -> col0,val0
                ub[j] = __shfl(ewb, idx);
            }
#pragma unroll
            for (int j = 0; j < 4; ++j) {
                ga[j] = *reinterpret_cast<const __half2*>(support + (size_t)(ua[j] & 0xFFFFu) * D + colbase);
                gb[j] = *reinterpret_cast<const __half2*>(support + (size_t)(ub[j] & 0xFFFFu) * D + colbase);
            }
#pragma unroll
            for (int j = 0; j < 4; ++j) {
                unsigned va2 = __builtin_amdgcn_perm(ua[j], ua[j], 0x07060706u); // (val,val)
                unsigned vb2 = __builtin_amdgcn_perm(ub[j], ub[j], 0x07060706u);
                acca = __hfma2(*reinterpret_cast<__half2*>(&va2), ga[j], acca);
                accb = __hfma2(*reinterpret_cast<__half2*>(&vb2), gb[j], accb);
            }
        }
        // combine the 4 edge groups
#pragma unroll
        for (int off = 16; off <= 32; off <<= 1) {
            int ia = __shfl_xor(*reinterpret_cast<int*>(&acca), off);
            int ib = __shfl_xor(*reinterpret_cast<int*>(&accb), off);
            acca = __hadd2(acca, *reinterpret_cast<__half2*>(&ia));
            accb = __hadd2(accb, *reinterpret_cast<__half2*>(&ib));
        }
        if (h == 0) {
            float2 fa = __half22float2(acca);
            *reinterpret_cast<__half2*>(outh + (size_t)row * D + colbase) = acca;
            s0 += fa.x; s1 += fa.y; q0 += fa.x * fa.x; q1 += fa.y * fa.y;
            if (rowb < N_NODES) {
                float2 fb = __half22float2(accb);
                *reinterpret_cast<__half2*>(outh + (size_t)rowb * D + colbase) = accb;
                s0 += fb.x; s1 += fb.y; q0 += fb.x * fb.x; q1 += fb.y * fb.y;
            }
        }
    }

    if (h == 0) {
        atomicAdd(&lsum[cl * 2 + 0], s0); atomicAdd(&lsum[cl * 2 + 1], s1);
        atomicAdd(&lsq[cl * 2 + 0], q0);  atomicAdd(&lsq[cl * 2 + 1], q1);
    }
    __syncthreads();
    if (tid < SCOLS) {
        atomicAdd(&colsum[slice * SCOLS + tid], lsum[tid]);
        atomicAdd(&colsq[slice * SCOLS + tid], lsq[tid]);
    }
}

// ---------------- BN + tanh: read fp16 outh, write fp32 out ----------------
__global__ __launch_bounds__(256) void bn_tanh_kernel(const __half* __restrict__ outh,
                                                      float* __restrict__ out,
                                                      const float* __restrict__ colsum,
                                                      const float* __restrict__ colsq,
                                                      const float* __restrict__ gamma,
                                                      const float* __restrict__ beta) {
    __shared__ float scale[D], shift[D];
    const int tid = threadIdx.x;
    if (tid < D) {
        float mean = colsum[tid] * (1.0f / N_NODES);
        float var  = colsq[tid] * (1.0f / N_NODES) - mean * mean;
        float sc   = rsqrtf(var + BN_EPS) * gamma[tid];
        scale[tid] = sc;
        shift[tid] = beta[tid] - mean * sc;
    }
    __syncthreads();
    const int nq = N_NODES * D / 8;   // units of 8 halves
    for (int i = blockIdx.x * 256 + tid; i < nq; i += gridDim.x * 256) {
        uint4 v = reinterpret_cast<const uint4*>(outh)[i];
        const int c = (i & 15) * 8;
        float r[8];
        float2 f;
        f = __half22float2(*reinterpret_cast<__half2*>(&v.x)); r[0] = f.x; r[1] = f.y;
        f = __half22float2(*reinterpret_cast<__half2*>(&v.y)); r[2] = f.x; r[3] = f.y;
        f = __half22float2(*reinterpret_cast<__half2*>(&v.z)); r[4] = f.x; r[5] = f.y;
        f = __half22float2(*reinterpret_cast<__half2*>(&v.w)); r[6] = f.x; r[7] = f.y;
#pragma unroll
        for (int k = 0; k < 8; ++k) {
            float x = r[k] * scale[c + k] + shift[c + k];
            float e = __expf(2.0f * x);
            r[k] = 1.0f - 2.0f / (1.0f + e);
        }
        float4 o0 = make_float4(r[0], r[1], r[2], r[3]);
        float4 o1 = make_float4(r[4], r[5], r[6], r[7]);
        reinterpret_cast<float4*>(out)[i * 2 + 0] = o0;
        reinterpret_cast<float4*>(out)[i * 2 + 1] = o1;
    }
}

// ---------------- launch ----------------
extern "C" void kernel_launch(void* const* d_in, const int* in_sizes, int n_in,
                              void* d_out, int out_size, void* d_ws, size_t ws_size,
                              hipStream_t stream) {
    const float* input  = (const float*)d_in[0];
    const int*   arow   = (const int*)d_in[1];
    const int*   acol   = (const int*)d_in[2];
    const float* aval   = (const float*)d_in[3];
    const float* weight = (const float*)d_in[4];
    const float* gamma  = (const float*)d_in[5];
    const float* beta   = (const float*)d_in[6];
    float* out = (float*)d_out;

    __half*   support = (__half*)d_ws;                              // 12.8 MB
    unsigned* bucket  = (unsigned*)(support + (size_t)N_NODES * D); // 12.8 MB
    __half*   outh    = (__half*)(bucket + (size_t)N_NODES * CAP);  // 12.8 MB
    uint2*    epack   = (uint2*)outh;                               // aliases outh (consumed before spmm writes)
    int*      cnt     = (int*)(outh + (size_t)N_NODES * D);         // 200 KB
    float*    colsum  = (float*)(cnt + N_NODES);                    // 128 (+128 colsq)
    __half*   Ht      = (__half*)(colsum + 2 * D);                  // 32 KB

    setup_pack_kernel<<<782, 256, 0, stream>>>(weight, Ht, cnt, colsum,
                                               arow, acol, aval, epack);
    gemm_scatter_kernel<<<SPMM_BLOCKS, 512, 0, stream>>>(epack, cnt, bucket,
                                                         input, Ht, support);
    spmm_kernel<<<SPMM_BLOCKS, 256, 0, stream>>>(support, cnt, bucket, outh, colsum, colsum + D);
    bn_tanh_kernel<<<2048, 256, 0, stream>>>(outh, out, colsum, colsum + D, gamma, beta);
}

// Round 17
// 101.702 us; speedup vs baseline: 1.1445x; 1.1112x over previous
//
#include <hip/hip_runtime.h>
#include <hip/hip_fp16.h>
#include <math.h>

#define N_NODES 50000
#define N_EDGES 800000
#define D 128
#define BN_EPS 1e-5f
#define N_TILES 3125   // 50000 / 16
#define CAP 64         // bucket capacity per row
#define SPMM_BLOCKS 2048
#define SCOLS 32       // columns per XCD-pinned slice in spmm
#define BINS 256       // row bins for the sort-based build
#define RPB 196        // rows per bin (256*196 = 50176 >= N_NODES)
#define EPB 3125       // edges per sort block (256*3125 = 800000)
#define SORTB 256      // sort blocks
#define BCAP 4096      // segment capacity per bin (mean 3125, +17 sigma)
#define GEMMB 782      // gemm blocks (ceil(3125/4))

typedef __attribute__((ext_vector_type(8))) _Float16 half8;
typedef __attribute__((ext_vector_type(4))) float floatx4;

// ---------------- octonion Hamilton tables ----------------
__device__ __constant__ int OCT_C[8][8] = {
    {0,1,2,3,4,5,6,7},
    {1,0,3,2,5,4,7,6},
    {2,3,0,1,6,7,4,5},
    {3,2,1,0,7,6,5,4},
    {4,5,6,7,0,1,2,3},
    {5,4,7,6,1,0,3,2},
    {6,7,4,5,2,3,0,1},
    {7,6,5,4,3,2,1,0}};
__device__ __constant__ float OCT_S[8][8] = {
    { 1,-1,-1,-1,-1,-1,-1,-1},
    { 1, 1,-1, 1,-1, 1, 1,-1},
    { 1, 1, 1,-1,-1,-1, 1, 1},
    { 1,-1, 1, 1,-1, 1,-1, 1},
    { 1, 1, 1, 1, 1,-1,-1,-1},
    { 1,-1, 1,-1, 1, 1, 1,-1},
    { 1,-1,-1, 1, 1,-1, 1, 1},
    { 1, 1,-1,-1, 1, 1,-1, 1}};

// ---------------- setup: Ht + zero stats/bintail ----------------
__global__ __launch_bounds__(256) void setup_kernel(const float* __restrict__ W,
                                                    __half* __restrict__ Ht,
                                                    float* __restrict__ stats,
                                                    int* __restrict__ bintail) {
    const int i = blockIdx.x * 256 + threadIdx.x;   // 64 blocks -> 16384
    if (i < D * D) {
        int ccol = i >> 7, k = i & 127;
        int ii = k >> 4, kw = k & 15, j = ccol >> 4, m = ccol & 15;
        Ht[i] = __float2half(OCT_S[j][ii] * W[kw * D + OCT_C[j][ii] * 16 + m]);
    }
    if (i < 2 * D) stats[i] = 0.0f;
    if (i < BINS * 16) bintail[i] = 0;
}

// ---------------- k2: role-split — blocks [0,256) sort edges into row bins,
// blocks [256,1038) run the MFMA gemm. 1038 blocks all co-resident -> overlap.
__global__ __launch_bounds__(256) void sortgemm_kernel(const int* __restrict__ arow,
                                                       const int* __restrict__ acol,
                                                       const float* __restrict__ aval,
                                                       int* __restrict__ bintail,
                                                       uint2* __restrict__ binned,
                                                       const float* __restrict__ in,
                                                       const __half* __restrict__ Ht,
                                                       __half* __restrict__ support) {
    __shared__ int hist[BINS], lbase[BINS], hist2[BINS];
    const int b = blockIdx.x;
    const int tid = threadIdx.x;
    if (b < SORTB) {
        // ---- sort: pass 1 histogram ----
        hist[tid] = 0;
        __syncthreads();
        const int e0 = b * EPB, e1 = e0 + EPB;
        for (int i = e0 + tid; i < e1; i += 256) {
            int bin = arow[i] / RPB;
            atomicAdd(&hist[bin], 1);
        }
        __syncthreads();
        // ---- reserve segment space: 1 global atomic per (block,bin) ----
        lbase[tid] = atomicAdd(&bintail[tid * 16], hist[tid]);
        hist2[tid] = 0;
        __syncthreads();
        // ---- pass 2: write edges into bin segments ----
        for (int i = e0 + tid; i < e1; i += 256) {
            int r = arow[i];
            int bin = r / RPB;
            unsigned hv = (unsigned)__half_as_ushort(__float2half(aval[i]));
            unsigned pk = ((unsigned)acol[i] & 0xFFFFu) | (hv << 16);
            int k = atomicAdd(&hist2[bin], 1);
            int idx = lbase[bin] + k;
            if (idx < BCAP) binned[(size_t)bin * BCAP + idx] = make_uint2(pk, (unsigned)r);
        }
        return;
    }
    // ---- gemm: tile = (b-SORTB)*4 + wave ----
    const int wv = tid >> 6;
    const int tile = (b - SORTB) * 4 + wv;
    if (tile >= N_TILES) return;
    const int lane = tid & 63;
    const int s = lane & 15;
    const int t = lane >> 4;

    half8 bb[8][4];
#pragma unroll
    for (int kk = 0; kk < 4; ++kk)
#pragma unroll
        for (int n = 0; n < 8; ++n)
            bb[n][kk] = *reinterpret_cast<const half8*>(Ht + (size_t)(16 * n + s) * D + kk * 32 + 8 * t);

    const float* ap = in + (size_t)(tile * 16 + s) * D;
    half8 a[4];
#pragma unroll
    for (int kk = 0; kk < 4; ++kk) {
        float4 f0 = *reinterpret_cast<const float4*>(ap + kk * 32 + 8 * t);
        float4 f1 = *reinterpret_cast<const float4*>(ap + kk * 32 + 8 * t + 4);
        a[kk][0] = (_Float16)f0.x; a[kk][1] = (_Float16)f0.y;
        a[kk][2] = (_Float16)f0.z; a[kk][3] = (_Float16)f0.w;
        a[kk][4] = (_Float16)f1.x; a[kk][5] = (_Float16)f1.y;
        a[kk][6] = (_Float16)f1.z; a[kk][7] = (_Float16)f1.w;
    }

    floatx4 acc[8];
#pragma unroll
    for (int n = 0; n < 8; ++n) acc[n] = (floatx4){0.f, 0.f, 0.f, 0.f};
#pragma unroll
    for (int kk = 0; kk < 4; ++kk)
#pragma unroll
        for (int n = 0; n < 8; ++n)
            acc[n] = __builtin_amdgcn_mfma_f32_16x16x32_f16(a[kk], bb[n][kk], acc[n], 0, 0, 0);

    __half* sp = support + (size_t)(tile * 16 + 4 * t) * D + s;
#pragma unroll
    for (int r = 0; r < 4; ++r)
#pragma unroll
        for (int n = 0; n < 8; ++n)
            sp[(size_t)r * D + 16 * n] = __float2half(acc[n][r]);
}

// ---------------- k3: bucket build — 1 block per bin, LDS slot counters ----------------
// No global atomics: slots from LDS atomicAdd; bucket region (196*256B=50KB) L2-hot.
__global__ __launch_bounds__(256) void bucket_kernel(const int* __restrict__ bintail,
                                                     const uint2* __restrict__ binned,
                                                     int* __restrict__ cnt,
                                                     unsigned* __restrict__ bucket) {
    __shared__ int lcnt[RPB];
    const int b = blockIdx.x;
    const int tid = threadIdx.x;
    if (tid < RPB) lcnt[tid] = 0;
    __syncthreads();
    const int nb = bintail[b * 16];
    const uint2* seg = binned + (size_t)b * BCAP;
    const int rbase = b * RPB;
    for (int i = tid; i < nb; i += 256) {
        uint2 e = seg[i];
        int rl = (int)e.y - rbase;
        int slot = atomicAdd(&lcnt[rl], 1);
        if (slot < CAP) bucket[(size_t)(rbase + rl) * CAP + slot] = e.x;
    }
    __syncthreads();
    if (tid < RPB && rbase + tid < N_NODES) cnt[rbase + tid] = lcnt[tid];
}

// ---------------- XCD-sliced bucket spmm, 2 rows/wave, pk_fma_f16 (R9 known-good) ----------------
__global__ __launch_bounds__(256) void spmm_kernel(const __half* __restrict__ support,
                                                   const int* __restrict__ cnt,
                                                   const unsigned* __restrict__ bucket,
                                                   __half* __restrict__ outh,
                                                   float* __restrict__ colsum,
                                                   float* __restrict__ colsq) {
    const int tid = threadIdx.x;
    const int lane = tid & 63;
    const int wv = tid >> 6;
    const int h = lane >> 4;          // edge group 0..3
    const int cl = lane & 15;         // column lane
    const int b = blockIdx.x;
    const int slice = (b & 7) >> 1;
    const int rank = ((b >> 3) << 1) | (b & 1);   // 0..511 within slice
    const int nrank = SPMM_BLOCKS >> 2;           // 512
    const int colbase = slice * SCOLS + cl * 2;

    __shared__ float lsum[SCOLS], lsq[SCOLS];
    if (tid < SCOLS) { lsum[tid] = 0.f; lsq[tid] = 0.f; }
    __syncthreads();

    float s0 = 0.f, s1 = 0.f, q0 = 0.f, q1 = 0.f;

    for (int row = rank * 8 + wv * 2; row < N_NODES; row += nrank * 8) {
        const int rowb = row + 1;
        int na = cnt[row]; na = na < CAP ? na : CAP;
        int nb = (rowb < N_NODES) ? cnt[rowb] : 0; nb = nb < CAP ? nb : CAP;
        const unsigned ewa = (lane < na) ? bucket[(size_t)row * CAP + lane] : 0u;
        const unsigned ewb = (lane < nb) ? bucket[(size_t)rowb * CAP + lane] : 0u;
        __half2 acca = __half2half2(__ushort_as_half((unsigned short)0));
        __half2 accb = acca;
        const int nmax = na > nb ? na : nb;
        const int n16 = (nmax + 15) & ~15;
        for (int e = 0; e < n16; e += 16) {
            unsigned ua[4], ub[4];
            __half2 ga[4], gb[4];
#pragma unroll
            for (int j = 0; j < 4; ++j) {
                int idx = e + j * 4 + h;
                ua[j] = __shfl(ewa, idx);       // idx>=n lanes broadcast 0 -> col0,val0
                ub[j] = __shfl(ewb, idx);
            }
#pragma unroll
            for (int j = 0; j < 4; ++j) {
                ga[j] = *reinterpret_cast<const __half2*>(support + (size_t)(ua[j] & 0xFFFFu) * D + colbase);
                gb[j] = *reinterpret_cast<const __half2*>(support + (size_t)(ub[j] & 0xFFFFu) * D + colbase);
            }
#pragma unroll
            for (int j = 0; j < 4; ++j) {
                unsigned va2 = __builtin_amdgcn_perm(ua[j], ua[j], 0x07060706u); // (val,val)
                unsigned vb2 = __builtin_amdgcn_perm(ub[j], ub[j], 0x07060706u);
                acca = __hfma2(*reinterpret_cast<__half2*>(&va2), ga[j], acca);
                accb = __hfma2(*reinterpret_cast<__half2*>(&vb2), gb[j], accb);
            }
        }
        // combine the 4 edge groups
#pragma unroll
        for (int off = 16; off <= 32; off <<= 1) {
            int ia = __shfl_xor(*reinterpret_cast<int*>(&acca), off);
            int ib = __shfl_xor(*reinterpret_cast<int*>(&accb), off);
            acca = __hadd2(acca, *reinterpret_cast<__half2*>(&ia));
            accb = __hadd2(accb, *reinterpret_cast<__half2*>(&ib));
        }
        if (h == 0) {
            float2 fa = __half22float2(acca);
            *reinterpret_cast<__half2*>(outh + (size_t)row * D + colbase) = acca;
            s0 += fa.x; s1 += fa.y; q0 += fa.x * fa.x; q1 += fa.y * fa.y;
            if (rowb < N_NODES) {
                float2 fb = __half22float2(accb);
                *reinterpret_cast<__half2*>(outh + (size_t)rowb * D + colbase) = accb;
                s0 += fb.x; s1 += fb.y; q0 += fb.x * fb.x; q1 += fb.y * fb.y;
            }
        }
    }

    if (h == 0) {
        atomicAdd(&lsum[cl * 2 + 0], s0); atomicAdd(&lsum[cl * 2 + 1], s1);
        atomicAdd(&lsq[cl * 2 + 0], q0);  atomicAdd(&lsq[cl * 2 + 1], q1);
    }
    __syncthreads();
    if (tid < SCOLS) {
        atomicAdd(&colsum[slice * SCOLS + tid], lsum[tid]);
        atomicAdd(&colsq[slice * SCOLS + tid], lsq[tid]);
    }
}

// ---------------- BN + tanh: read fp16 outh, write fp32 out ----------------
__global__ __launch_bounds__(256) void bn_tanh_kernel(const __half* __restrict__ outh,
                                                      float* __restrict__ out,
                                                      const float* __restrict__ colsum,
                                                      const float* __restrict__ colsq,
                                                      const float* __restrict__ gamma,
                                                      const float* __restrict__ beta) {
    __shared__ float scale[D], shift[D];
    const int tid = threadIdx.x;
    if (tid < D) {
        float mean = colsum[tid] * (1.0f / N_NODES);
        float var  = colsq[tid] * (1.0f / N_NODES) - mean * mean;
        float sc   = rsqrtf(var + BN_EPS) * gamma[tid];
        scale[tid] = sc;
        shift[tid] = beta[tid] - mean * sc;
    }
    __syncthreads();
    const int nq = N_NODES * D / 8;   // units of 8 halves
    for (int i = blockIdx.x * 256 + tid; i < nq; i += gridDim.x * 256) {
        uint4 v = reinterpret_cast<const uint4*>(outh)[i];
        const int c = (i & 15) * 8;
        float r[8];
        float2 f;
        f = __half22float2(*reinterpret_cast<__half2*>(&v.x)); r[0] = f.x; r[1] = f.y;
        f = __half22float2(*reinterpret_cast<__half2*>(&v.y)); r[2] = f.x; r[3] = f.y;
        f = __half22float2(*reinterpret_cast<__half2*>(&v.z)); r[4] = f.x; r[5] = f.y;
        f = __half22float2(*reinterpret_cast<__half2*>(&v.w)); r[6] = f.x; r[7] = f.y;
#pragma unroll
        for (int k = 0; k < 8; ++k) {
            float x = r[k] * scale[c + k] + shift[c + k];
            float e = __expf(2.0f * x);
            r[k] = 1.0f - 2.0f / (1.0f + e);
        }
        float4 o0 = make_float4(r[0], r[1], r[2], r[3]);
        float4 o1 = make_float4(r[4], r[5], r[6], r[7]);
        reinterpret_cast<float4*>(out)[i * 2 + 0] = o0;
        reinterpret_cast<float4*>(out)[i * 2 + 1] = o1;
    }
}

// ---------------- launch ----------------
extern "C" void kernel_launch(void* const* d_in, const int* in_sizes, int n_in,
                              void* d_out, int out_size, void* d_ws, size_t ws_size,
                              hipStream_t stream) {
    const float* input  = (const float*)d_in[0];
    const int*   arow   = (const int*)d_in[1];
    const int*   acol   = (const int*)d_in[2];
    const float* aval   = (const float*)d_in[3];
    const float* weight = (const float*)d_in[4];
    const float* gamma  = (const float*)d_in[5];
    const float* beta   = (const float*)d_in[6];
    float* out = (float*)d_out;

    __half*   support = (__half*)d_ws;                              // 12.8 MB
    unsigned* bucket  = (unsigned*)(support + (size_t)N_NODES * D); // 12.8 MB
    __half*   outh    = (__half*)(bucket + (size_t)N_NODES * CAP);  // 12.8 MB
    uint2*    binned  = (uint2*)outh;                               // 8.4 MB, consumed before spmm writes outh
    int*      cnt     = (int*)(outh + (size_t)N_NODES * D);         // 200 KB
    float*    colsum  = (float*)(cnt + N_NODES);                    // 128 (+128 colsq)
    int*      bintail = (int*)(colsum + 2 * D);                     // 16 KB (64B-strided)
    __half*   Ht      = (__half*)(bintail + BINS * 16);             // 32 KB

    setup_kernel<<<64, 256, 0, stream>>>(weight, Ht, colsum, bintail);
    sortgemm_kernel<<<SORTB + GEMMB, 256, 0, stream>>>(arow, acol, aval, bintail, binned,
                                                       input, Ht, support);
    bucket_kernel<<<BINS, 256, 0, stream>>>(bintail, binned, cnt, bucket);
    spmm_kernel<<<SPMM_BLOCKS, 256, 0, stream>>>(support, cnt, bucket, outh, colsum, colsum + D);
    bn_tanh_kernel<<<2048, 256, 0, stream>>>(outh, out, colsum, colsum + D, gamma, beta);
}